// Round 5
// baseline (2217.936 us; speedup 1.0000x reference)
//
#include <hip/hip_runtime.h>
#include <hip/hip_bf16.h>
#include <type_traits>

using bf16 = __hip_bfloat16;

namespace {

constexpr int B_ = 2;
constexpr int N_ = 4096;
constexpr int C_ = 64;
constexpr int K14_ = 14;
constexpr int KX_ = 8;
constexpr int KP_ = 6;
constexpr int K2_ = 32;
constexpr int OC_ = 64;

// ---------------- x squared norms (f32) ----------------
__global__ __launch_bounds__(256)
void xnorm_kernel(const float* __restrict__ x, float* __restrict__ nx)
{
  int p = blockIdx.x * 256 + threadIdx.x;
  if (p >= B_ * N_) return;
  float s = 0.f;
#pragma unroll 8
  for (int c = 0; c < C_; ++c) { float v = x[p * C_ + c]; s = fmaf(v, v, s); }
  nx[p] = s;
}

// ---------------- weight prep: split + transpose ----------------
__global__ __launch_bounds__(256)
void wprep_kernel(const float* __restrict__ W1, const float* __restrict__ W2,
                  const float* __restrict__ W3,
                  float* __restrict__ WT1a, float* __restrict__ WT1bm,
                  float* __restrict__ WT2a, float* __restrict__ WT2bm,
                  float* __restrict__ W3T)
{
  int idx = blockIdx.x * 256 + threadIdx.x;
  if (idx < 128 * 128) {
    int o = idx & 127, c = idx >> 7;
    float a = W2[o * 256 + c];
    WT2a[c * 128 + o] = a;
    WT2bm[c * 128 + o] = W2[o * 256 + 128 + c] - a;
    if (c < 64) {
      float a1 = W1[o * 128 + c];
      WT1a[c * 128 + o] = a1;
      WT1bm[c * 128 + o] = W1[o * 128 + 64 + c] - a1;
    }
  }
  if (idx < 64 * 128) {
    int oo = idx & 63, c = idx >> 6;
    W3T[c * 64 + oo] = W3[oo * 128 + c];
  }
}

// ---------------- knn over x (f32; feeds out only, threshold-tolerant) ----------------
__global__ __launch_bounds__(512, 2)
void knn_x_kernel(const float* __restrict__ x, const float* __restrict__ nx,
                  int* __restrict__ idx1)
{
  constexpr int TJ = 128;
  __shared__ float qs[8][C_];
  __shared__ float tile[C_][TJ + 1];
  const int wave = threadIdx.x >> 6, lane = threadIdx.x & 63;
  const int qg = blockIdx.x * 8 + wave;          // 1024 blocks * 8 waves = 8192
  const int bb = qg >> 12;
  const float* xb = x + bb * N_ * C_;
  qs[wave][lane] = x[qg * C_ + lane];            // C_==64 == wave width
  const float nq = nx[qg];
  const float* nb_ = nx + bb * N_;
  float dst[64];
#pragma unroll
  for (int ti = 0; ti < N_ / TJ; ++ti) {
    __syncthreads();
    for (int e = threadIdx.x; e < C_ * TJ; e += 512) {
      int j = e >> 6, c = e & 63;
      tile[c][j] = xb[(ti * TJ + j) * C_ + c];
    }
    __syncthreads();
#pragma unroll
    for (int tr = 0; tr < 2; ++tr) {
      const int t = ti * 2 + tr;
      float acc = 0.f;
#pragma unroll
      for (int c = 0; c < C_; ++c)
        acc = fmaf(qs[wave][c], tile[c][tr * 64 + lane], acc);
      dst[t] = nq + nb_[t * 64 + lane] - 2.f * acc;
    }
  }
  unsigned long long taken = 0ull;
  float bd = 3.0e38f; int bt = 0;
#pragma unroll
  for (int tt = 0; tt < 64; ++tt) {
    bool b = dst[tt] < bd; bd = b ? dst[tt] : bd; bt = b ? tt : bt;
  }
  for (int r = 0; r < KX_ + 1; ++r) {
    float d = bd; int j = bt * 64 + lane;
#pragma unroll
    for (int m = 1; m < 64; m <<= 1) {
      float od = __shfl_xor(d, m, 64);
      int oj = __shfl_xor(j, m, 64);
      if (od < d || (od == d && oj < j)) { d = od; j = oj; }
    }
    if (r > 0 && lane == 0) idx1[qg * K14_ + (r - 1)] = j;
    if ((j & 63) == lane) {
      taken |= 1ull << (j >> 6);
      bd = 3.0e38f; bt = 0;
#pragma unroll
      for (int tt = 0; tt < 64; ++tt) {
        bool use = ((taken >> tt) & 1ull) == 0ull;
        bool b = use && (dst[tt] < bd); bd = b ? dst[tt] : bd; bt = b ? tt : bt;
      }
    }
  }
}

// ---------------- knn over pos: replicate np f32 with FMA dot (graded idx2) ------
// norms: individually-rounded products, sequential adds (np.sum(a*a)).
// dot:   fma(a2,b2, fma(a1,b1, fl(a0*b0)))  — numpy AVX2-dispatch einsum tail /
//        Eigen/BLAS sgemm K=3 / XLA-CPU all produce this.
// d = fl(fl(nq+nj) - fl(2*dot)).
__global__ __launch_bounds__(512, 2)
void knn_pos_kernel(const float* __restrict__ pos,
                    int* __restrict__ idx1, int* __restrict__ idx2,
                    float* __restrict__ oidx)
{
#pragma clang fp contract(off)
  __shared__ float pL[3][N_];     // 48 KB
  __shared__ float nL[N_];        // 16 KB
  const int wave = threadIdx.x >> 6, lane = threadIdx.x & 63;
  const int qg = blockIdx.x * 8 + wave;
  const int bb = qg >> 12;
  const float* pb = pos + bb * N_ * 3;
  for (int j = threadIdx.x; j < N_; j += 512) {
    float a = pb[j * 3], b = pb[j * 3 + 1], c = pb[j * 3 + 2];
    pL[0][j] = a; pL[1][j] = b; pL[2][j] = c;
    float aa = a * a;           // numpy: (a*a) elementwise, then sequential sum
    float bb2 = b * b;
    float cc = c * c;
    float s1 = aa + bb2;
    nL[j] = s1 + cc;
  }
  __syncthreads();
  const int q = qg & (N_ - 1);
  const float qx = pL[0][q], qy = pL[1][q], qz = pL[2][q];
  const float nq = nL[q];
  float dst[64];
#pragma unroll
  for (int t = 0; t < 64; ++t) {
    int j = t * 64 + lane;
    float dot = qx * pL[0][j];           // fl(a0*b0)  (== fma(a0,b0,0))
    dot = fmaf(qy, pL[1][j], dot);       // fused
    dot = fmaf(qz, pL[2][j], dot);       // fused
    float t1 = nq + nL[j];
    float t2 = 2.0f * dot;
    dst[t] = t1 - t2;
  }
  unsigned long long taken = 0ull;
  float bd = 3.0e38f; int bt = 0;
#pragma unroll
  for (int tt = 0; tt < 64; ++tt) {
    bool b = dst[tt] < bd; bd = b ? dst[tt] : bd; bt = b ? tt : bt;
  }
  for (int r = 0; r < K2_ + 1; ++r) {
    float d = bd; int j = bt * 64 + lane;
#pragma unroll
    for (int m = 1; m < 64; m <<= 1) {
      float od = __shfl_xor(d, m, 64);
      int oj = __shfl_xor(j, m, 64);
      if (od < d || (od == d && oj < j)) { d = od; j = oj; }
    }
    if (r > 0 && lane == 0) {
      int rr = r - 1;
      if (rr < KP_) idx1[qg * K14_ + KX_ + rr] = j;
      idx2[qg * K2_ + rr] = j;
      oidx[qg * K2_ + rr] = (float)j;     // d_out is float: idx as float value
    }
    if ((j & 63) == lane) {
      taken |= 1ull << (j >> 6);
      bd = 3.0e38f; bt = 0;
#pragma unroll
      for (int tt = 0; tt < 64; ++tt) {
        bool use = ((taken >> tt) & 1ull) == 0ull;
        bool b = use && (dst[tt] < bd); bd = b ? dst[tt] : bd; bt = b ? tt : bt;
      }
    }
  }
}

// ---------------- per-point projection ----------------
template<int CIN, typename TIN>
__global__ __launch_bounds__(256)
void lin_kernel(const TIN* __restrict__ in, const float* __restrict__ WT,
                bf16* __restrict__ out)
{
  __shared__ float wt[CIN * 128];
  for (int e = threadIdx.x; e < CIN * 128; e += 256) wt[e] = WT[e];
  __syncthreads();
  const int which = threadIdx.x >> 7, o = threadIdx.x & 127;
  for (int p0 = blockIdx.x * 2; p0 < B_ * N_; p0 += gridDim.x * 2) {
    int p = p0 + which;
    float acc = 0.f;
#pragma unroll 8
    for (int c = 0; c < CIN; ++c) {
      float v;
      if constexpr (std::is_same_v<TIN, float>) v = in[p * CIN + c];
      else v = __bfloat162float(in[p * CIN + c]);
      acc = fmaf(wt[c * 128 + o], v, acc);
    }
    out[p * 128 + o] = __float2bfloat16(acc);
  }
}

// ---------------- BN stats over gathered y = a[nbr] + ac[ctr] ----------------
template<int KNB>
__global__ __launch_bounds__(256)
void stats_gather_kernel(const bf16* __restrict__ a, const bf16* __restrict__ ac,
                         const int* __restrict__ nbr, double* __restrict__ st)
{
  const int o = threadIdx.x & 127;
  const int which = threadIdx.x >> 7;
  double s = 0.0, s2 = 0.0;
  const int E = B_ * N_ * KNB;
  for (int e0 = blockIdx.x * 2; e0 < E; e0 += gridDim.x * 2) {
    int e = e0 + which;
    int p = e / KNB;
    int nb = nbr[e] & (N_ - 1);
    int base = (p >> 12) << 12;
    float y = __bfloat162float(a[(base + nb) * 128 + o]) + __bfloat162float(ac[p * 128 + o]);
    s += (double)y; s2 += (double)y * (double)y;
  }
  atomicAdd(&st[o], s);
  atomicAdd(&st[128 + o], s2);
}

// ---------------- BN finalize ----------------
__global__ void bnfin_kernel(const double* __restrict__ st, const float* __restrict__ g,
                             const float* __restrict__ bi, float* __restrict__ so,
                             int nch, double cnt)
{
  int o = threadIdx.x;
  if (o >= nch) return;
  double mu = st[o] / cnt;
  double var = st[nch + o] / cnt - mu * mu;
  double sc = (double)g[o] / sqrt(var + 1e-5);
  so[o] = (float)sc;
  so[nch + o] = (float)((double)bi[o] - mu * sc);
}

// ---------------- h1 = max_k lrelu(bn(u[nbr]+uc[ctr])) ----------------
__global__ __launch_bounds__(256)
void h1_kernel(const bf16* __restrict__ u, const bf16* __restrict__ uc,
               const int* __restrict__ idx1, const float* __restrict__ so,
               bf16* __restrict__ h1)
{
  const int o = threadIdx.x & 127, which = threadIdx.x >> 7;
  float sc = so[o], off = so[128 + o];
  for (int p0 = blockIdx.x * 2; p0 < B_ * N_; p0 += gridDim.x * 2) {
    int p = p0 + which;
    int base = (p >> 12) << 12;
    float ucv = __bfloat162float(uc[p * 128 + o]);
    float m = -3.0e38f;
#pragma unroll
    for (int kk = 0; kk < K14_; ++kk) {
      int nb = idx1[p * K14_ + kk] & (N_ - 1);
      float y = __bfloat162float(u[(base + nb) * 128 + o]) + ucv;
      float v = fmaf(y, sc, off);
      v = v > 0.f ? v : 0.2f * v;
      m = fmaxf(m, v);
    }
    h1[p * 128 + o] = __float2bfloat16(m);
  }
}

// ---------------- conv3 stats ----------------
__global__ __launch_bounds__(256)
void stats3_kernel(const bf16* __restrict__ z, const bf16* __restrict__ zc,
                   const int* __restrict__ idx2, const float* __restrict__ so2,
                   const float* __restrict__ W3T, double* __restrict__ st3)
{
  __shared__ float w3[128 * 64];
  __shared__ float h2b[2][128];
  __shared__ float part[2][2][64];
  for (int e = threadIdx.x; e < 128 * 64; e += 256) w3[e] = W3T[e];
  const int which = threadIdx.x >> 7;
  const int o = threadIdx.x & 127;
  const int oo = threadIdx.x & 63;
  const int ch = (threadIdx.x >> 6) & 1;
  float sc = so2[o], off = so2[128 + o];
  double s = 0.0, s2 = 0.0;
  const int E = B_ * N_ * K2_;
  __syncthreads();
  for (int e0 = blockIdx.x * 2; e0 < E; e0 += gridDim.x * 2) {
    int e = e0 + which;
    int p = e >> 5;
    int nb = idx2[e] & (N_ - 1);
    int base = (p >> 12) << 12;
    float y = __bfloat162float(z[(base + nb) * 128 + o]) + __bfloat162float(zc[p * 128 + o]);
    float v = fmaf(y, sc, off);
    h2b[which][o] = v > 0.f ? v : 0.2f * v;
    __syncthreads();
    float acc = 0.f;
#pragma unroll
    for (int c = 0; c < 64; ++c) {
      int cc = ch * 64 + c;
      acc = fmaf(w3[cc * 64 + oo], h2b[which][cc], acc);
    }
    part[which][ch][oo] = acc;
    __syncthreads();
    if (ch == 0) {
      float y3 = part[which][0][oo] + part[which][1][oo];
      s += (double)y3; s2 += (double)y3 * (double)y3;
    }
    __syncthreads();
  }
  if (ch == 0) {
    atomicAdd(&st3[oo], s);
    atomicAdd(&st3[64 + oo], s2);
  }
}

// ---------------- final output (float) ----------------
__global__ __launch_bounds__(256)
void out_kernel(const bf16* __restrict__ z, const bf16* __restrict__ zc,
                const int* __restrict__ idx2, const float* __restrict__ so2,
                const float* __restrict__ so3, const float* __restrict__ W3T,
                float* __restrict__ outp)
{
  __shared__ float w3[128 * 64];
  __shared__ float h2b[2][128];
  __shared__ float part[2][2][64];
  __shared__ float mx[2][64];
  for (int e = threadIdx.x; e < 128 * 64; e += 256) w3[e] = W3T[e];
  const int which = threadIdx.x >> 7;
  const int o = threadIdx.x & 127;
  const int oo = threadIdx.x & 63;
  const int ch = (threadIdx.x >> 6) & 1;
  float sc = so2[o], off = so2[128 + o];
  float sc3 = so3[oo], off3 = so3[64 + oo];
  __syncthreads();
  for (int p = blockIdx.x; p < B_ * N_; p += gridDim.x) {
    int base = (p >> 12) << 12;
    float zcv = __bfloat162float(zc[p * 128 + o]);
    float m = -3.0e38f;
    for (int k0 = 0; k0 < K2_; k0 += 2) {
      int kk = k0 + which;
      int nb = idx2[p * K2_ + kk] & (N_ - 1);
      float y = __bfloat162float(z[(base + nb) * 128 + o]) + zcv;
      float v = fmaf(y, sc, off);
      h2b[which][o] = v > 0.f ? v : 0.2f * v;
      __syncthreads();
      float acc = 0.f;
#pragma unroll
      for (int c = 0; c < 64; ++c) {
        int cc = ch * 64 + c;
        acc = fmaf(w3[cc * 64 + oo], h2b[which][cc], acc);
      }
      part[which][ch][oo] = acc;
      __syncthreads();
      if (ch == 0) {
        float y3 = part[which][0][oo] + part[which][1][oo];
        float v3 = fmaf(y3, sc3, off3);
        v3 = v3 > 0.f ? v3 : 0.2f * v3;
        m = fmaxf(m, v3);
      }
      __syncthreads();
    }
    if (ch == 0) mx[which][oo] = m;
    __syncthreads();
    if (threadIdx.x < 64) {
      outp[p * OC_ + threadIdx.x] = fmaxf(mx[0][threadIdx.x], mx[1][threadIdx.x]);
    }
    __syncthreads();
  }
}

} // namespace

extern "C" void kernel_launch(void* const* d_in, const int* in_sizes, int n_in,
                              void* d_out, int out_size, void* d_ws, size_t ws_size,
                              hipStream_t stream) {
  const float* x   = (const float*)d_in[0];
  const float* pos = (const float*)d_in[1];
  const float* W1  = (const float*)d_in[2];
  const float* g1  = (const float*)d_in[3];
  const float* b1  = (const float*)d_in[4];
  const float* W2  = (const float*)d_in[5];
  const float* g2  = (const float*)d_in[6];
  const float* b2  = (const float*)d_in[7];
  const float* W3  = (const float*)d_in[8];
  const float* g3  = (const float*)d_in[9];
  const float* b3  = (const float*)d_in[10];

  float* outp = (float*)d_out;                 // [B*N*64] float
  float* oidx = outp + B_ * N_ * OC_;          // [B*N*32] idx2 as float values

  // ---- workspace layout (~8 MB; critical arrays first) ----
  char* w = (char*)d_ws;
  double* stats = (double*)w;            w += 640 * sizeof(double);
  float* nxf    = (float*)w;             w += B_ * N_ * 4;
  float* WT1a   = (float*)w;             w += 64 * 128 * 4;
  float* WT1bm  = (float*)w;             w += 64 * 128 * 4;
  float* WT2a   = (float*)w;             w += 128 * 128 * 4;
  float* WT2bm  = (float*)w;             w += 128 * 128 * 4;
  float* W3T    = (float*)w;             w += 128 * 64 * 4;
  float* so1    = (float*)w;             w += 256 * 4;
  float* so2    = (float*)w;             w += 256 * 4;
  float* so3    = (float*)w;             w += 128 * 4;
  int* idx1     = (int*)w;               w += B_ * N_ * K14_ * 4;
  int* idx2i    = (int*)w;               w += B_ * N_ * K2_ * 4;
  bf16* u       = (bf16*)w;              w += B_ * N_ * 128 * 2;
  bf16* uc      = (bf16*)w;              w += B_ * N_ * 128 * 2;
  bf16* h1      = (bf16*)w;              w += B_ * N_ * 128 * 2;
  bf16* zz  = u;    // alias: u dead after h1_kernel
  bf16* zzc = uc;   // alias: uc dead after h1_kernel

  hipMemsetAsync(stats, 0, 640 * sizeof(double), stream);

  xnorm_kernel<<<(B_ * N_ + 255) / 256, 256, 0, stream>>>(x, nxf);
  wprep_kernel<<<64, 256, 0, stream>>>(W1, W2, W3, WT1a, WT1bm, WT2a, WT2bm, W3T);

  knn_x_kernel<<<1024, 512, 0, stream>>>(x, nxf, idx1);
  knn_pos_kernel<<<1024, 512, 0, stream>>>(pos, idx1, idx2i, oidx);

  lin_kernel<64, float><<<512, 256, 0, stream>>>(x, WT1a, u);
  lin_kernel<64, float><<<512, 256, 0, stream>>>(x, WT1bm, uc);

  stats_gather_kernel<K14_><<<512, 256, 0, stream>>>(u, uc, idx1, stats);
  bnfin_kernel<<<1, 128, 0, stream>>>(stats, g1, b1, so1, 128, (double)(B_ * N_ * K14_));
  h1_kernel<<<512, 256, 0, stream>>>(u, uc, idx1, so1, h1);

  lin_kernel<128, bf16><<<512, 256, 0, stream>>>(h1, WT2a, zz);
  lin_kernel<128, bf16><<<512, 256, 0, stream>>>(h1, WT2bm, zzc);

  stats_gather_kernel<K2_><<<512, 256, 0, stream>>>(zz, zzc, idx2i, stats + 256);
  bnfin_kernel<<<1, 128, 0, stream>>>(stats + 256, g2, b2, so2, 128, (double)(B_ * N_ * K2_));

  stats3_kernel<<<512, 256, 0, stream>>>(zz, zzc, idx2i, so2, W3T, stats + 512);
  bnfin_kernel<<<1, 128, 0, stream>>>(stats + 512, g3, b3, so3, 64, (double)(B_ * N_ * K2_));

  out_kernel<<<512, 256, 0, stream>>>(zz, zzc, idx2i, so2, so3, W3T, outp);
}

// Round 6
// 1014.974 us; speedup vs baseline: 2.1852x; 2.1852x over previous
//
#include <hip/hip_runtime.h>
#include <hip/hip_bf16.h>
#include <type_traits>

using bf16 = __hip_bfloat16;

namespace {

constexpr int B_ = 2;
constexpr int N_ = 4096;
constexpr int C_ = 64;
constexpr int K14_ = 14;
constexpr int KX_ = 8;
constexpr int KP_ = 6;
constexpr int K2_ = 32;
constexpr int OC_ = 64;

__device__ __forceinline__ float bflo(unsigned u) { return __uint_as_float(u << 16); }
__device__ __forceinline__ float bfhi(unsigned u) { return __uint_as_float(u & 0xffff0000u); }

// ---------------- x squared norms (f32) ----------------
__global__ __launch_bounds__(256)
void xnorm_kernel(const float* __restrict__ x, float* __restrict__ nx)
{
  int p = blockIdx.x * 256 + threadIdx.x;
  if (p >= B_ * N_) return;
  float s = 0.f;
#pragma unroll 8
  for (int c = 0; c < C_; ++c) { float v = x[p * C_ + c]; s = fmaf(v, v, s); }
  nx[p] = s;
}

// ---------------- weight prep: split + transpose ----------------
__global__ __launch_bounds__(256)
void wprep_kernel(const float* __restrict__ W1, const float* __restrict__ W2,
                  const float* __restrict__ W3,
                  float* __restrict__ WT1a, float* __restrict__ WT1bm,
                  float* __restrict__ WT2a, float* __restrict__ WT2bm,
                  float* __restrict__ W3T)
{
  int idx = blockIdx.x * 256 + threadIdx.x;
  if (idx < 128 * 128) {
    int o = idx & 127, c = idx >> 7;
    float a = W2[o * 256 + c];
    WT2a[c * 128 + o] = a;
    WT2bm[c * 128 + o] = W2[o * 256 + 128 + c] - a;
    if (c < 64) {
      float a1 = W1[o * 128 + c];
      WT1a[c * 128 + o] = a1;
      WT1bm[c * 128 + o] = W1[o * 128 + 64 + c] - a1;
    }
  }
  if (idx < 64 * 128) {
    int oo = idx & 63, c = idx >> 6;
    W3T[c * 64 + oo] = W3[oo * 128 + c];
  }
}

// ---------------- knn over x v2: bf16 tile, b64 reads, 4 acc/lane ----------------
// idx1 feeds values only (threshold-tolerant) -> bf16 neighbor rounding OK.
__global__ __launch_bounds__(512, 2)
void knn_x_kernel(const float* __restrict__ x, const float* __restrict__ nx,
                  int* __restrict__ idx1)
{
  constexpr int TJ = 256, PAD = 264;
  __shared__ float qs[8][C_];
  __shared__ unsigned short tile[C_ * PAD];   // [c][j] bf16, pad to kill write conflicts
  const int wave = threadIdx.x >> 6, lane = threadIdx.x & 63;
  const int qg = blockIdx.x * 8 + wave;       // 1024 blocks * 8 waves
  const int bb = qg >> 12;
  const float* xb = x + bb * N_ * C_;
  qs[wave][lane] = x[qg * C_ + lane];
  const float nq = nx[qg];
  const float* nb_ = nx + bb * N_;
  float dst[64];
#pragma unroll
  for (int ti = 0; ti < N_ / TJ; ++ti) {      // 16 tiles, dst statically indexed
    __syncthreads();
    for (int e = threadIdx.x; e < C_ * TJ; e += 512) {
      int c = e & 63, j = e >> 6;
      float v = xb[(ti * TJ + j) * C_ + c];
      tile[c * PAD + j] = (unsigned short)(__float_as_uint(v) >> 16);
    }
    __syncthreads();
    float4 nb4 = *(const float4*)&nb_[ti * TJ + 4 * lane];
    float a0 = 0.f, a1 = 0.f, a2 = 0.f, a3 = 0.f;
#pragma unroll 8
    for (int c = 0; c < C_; ++c) {
      unsigned long long vv = *(const unsigned long long*)&tile[c * PAD + 4 * lane];
      float q = qs[wave][c];
      unsigned lo = (unsigned)vv, hi = (unsigned)(vv >> 32);
      a0 = fmaf(q, bflo(lo), a0);
      a1 = fmaf(q, bfhi(lo), a1);
      a2 = fmaf(q, bflo(hi), a2);
      a3 = fmaf(q, bfhi(hi), a3);
    }
    dst[ti * 4 + 0] = nq + nb4.x - 2.f * a0;
    dst[ti * 4 + 1] = nq + nb4.y - 2.f * a1;
    dst[ti * 4 + 2] = nq + nb4.z - 2.f * a2;
    dst[ti * 4 + 3] = nq + nb4.w - 2.f * a3;
  }
  // selection: lane owns neighbors j with ((j>>2)&63)==lane; dst slot t=((j>>8)<<2)|(j&3)
  unsigned long long taken = 0ull;
  float bd = 3.0e38f; int bt = 0;
#pragma unroll
  for (int tt = 0; tt < 64; ++tt) {
    bool b = dst[tt] < bd; bd = b ? dst[tt] : bd; bt = b ? tt : bt;
  }
  for (int r = 0; r < KX_ + 1; ++r) {
    float d = bd; int j = (bt >> 2) * 256 + 4 * lane + (bt & 3);
#pragma unroll
    for (int m = 1; m < 64; m <<= 1) {
      float od = __shfl_xor(d, m, 64);
      int oj = __shfl_xor(j, m, 64);
      if (od < d || (od == d && oj < j)) { d = od; j = oj; }
    }
    if (r > 0 && lane == 0) idx1[qg * K14_ + (r - 1)] = j;
    if (((j >> 2) & 63) == lane) {
      taken |= 1ull << (((j >> 8) << 2) | (j & 3));
      bd = 3.0e38f; bt = 0;
#pragma unroll
      for (int tt = 0; tt < 64; ++tt) {
        bool use = ((taken >> tt) & 1ull) == 0ull;
        bool b = use && (dst[tt] < bd); bd = b ? dst[tt] : bd; bt = b ? tt : bt;
      }
    }
  }
}

// ---------------- knn over pos: bit-exact numpy-f32 (graded idx2) — UNCHANGED ----
__global__ __launch_bounds__(512, 2)
void knn_pos_kernel(const float* __restrict__ pos,
                    int* __restrict__ idx1, int* __restrict__ idx2,
                    float* __restrict__ oidx)
{
#pragma clang fp contract(off)
  __shared__ float pL[3][N_];
  __shared__ float nL[N_];
  const int wave = threadIdx.x >> 6, lane = threadIdx.x & 63;
  const int qg = blockIdx.x * 8 + wave;
  const int bb = qg >> 12;
  const float* pb = pos + bb * N_ * 3;
  for (int j = threadIdx.x; j < N_; j += 512) {
    float a = pb[j * 3], b = pb[j * 3 + 1], c = pb[j * 3 + 2];
    pL[0][j] = a; pL[1][j] = b; pL[2][j] = c;
    float aa = a * a;
    float bb2 = b * b;
    float cc = c * c;
    float s1 = aa + bb2;
    nL[j] = s1 + cc;
  }
  __syncthreads();
  const int q = qg & (N_ - 1);
  const float qx = pL[0][q], qy = pL[1][q], qz = pL[2][q];
  const float nq = nL[q];
  float dst[64];
#pragma unroll
  for (int t = 0; t < 64; ++t) {
    int j = t * 64 + lane;
    float dot = qx * pL[0][j];
    dot = fmaf(qy, pL[1][j], dot);
    dot = fmaf(qz, pL[2][j], dot);
    float t1 = nq + nL[j];
    float t2 = 2.0f * dot;
    dst[t] = t1 - t2;
  }
  unsigned long long taken = 0ull;
  float bd = 3.0e38f; int bt = 0;
#pragma unroll
  for (int tt = 0; tt < 64; ++tt) {
    bool b = dst[tt] < bd; bd = b ? dst[tt] : bd; bt = b ? tt : bt;
  }
  for (int r = 0; r < K2_ + 1; ++r) {
    float d = bd; int j = bt * 64 + lane;
#pragma unroll
    for (int m = 1; m < 64; m <<= 1) {
      float od = __shfl_xor(d, m, 64);
      int oj = __shfl_xor(j, m, 64);
      if (od < d || (od == d && oj < j)) { d = od; j = oj; }
    }
    if (r > 0 && lane == 0) {
      int rr = r - 1;
      if (rr < KP_) idx1[qg * K14_ + KX_ + rr] = j;
      idx2[qg * K2_ + rr] = j;
      oidx[qg * K2_ + rr] = (float)j;
    }
    if ((j & 63) == lane) {
      taken |= 1ull << (j >> 6);
      bd = 3.0e38f; bt = 0;
#pragma unroll
      for (int tt = 0; tt < 64; ++tt) {
        bool use = ((taken >> tt) & 1ull) == 0ull;
        bool b = use && (dst[tt] < bd); bd = b ? dst[tt] : bd; bt = b ? tt : bt;
      }
    }
  }
}

// ---------------- per-point projection ----------------
template<int CIN, typename TIN>
__global__ __launch_bounds__(256)
void lin_kernel(const TIN* __restrict__ in, const float* __restrict__ WT,
                bf16* __restrict__ out)
{
  __shared__ float wt[CIN * 128];
  for (int e = threadIdx.x; e < CIN * 128; e += 256) wt[e] = WT[e];
  __syncthreads();
  const int which = threadIdx.x >> 7, o = threadIdx.x & 127;
  for (int p0 = blockIdx.x * 2; p0 < B_ * N_; p0 += gridDim.x * 2) {
    int p = p0 + which;
    float acc = 0.f;
#pragma unroll 8
    for (int c = 0; c < CIN; ++c) {
      float v;
      if constexpr (std::is_same_v<TIN, float>) v = in[p * CIN + c];
      else v = __bfloat162float(in[p * CIN + c]);
      acc = fmaf(wt[c * 128 + o], v, acc);
    }
    out[p * 128 + o] = __float2bfloat16(acc);
  }
}

// ---------------- BN stats over gathered y = a[nbr] + ac[ctr] ----------------
template<int KNB>
__global__ __launch_bounds__(256)
void stats_gather_kernel(const bf16* __restrict__ a, const bf16* __restrict__ ac,
                         const int* __restrict__ nbr, double* __restrict__ st)
{
  const int o = threadIdx.x & 127;
  const int which = threadIdx.x >> 7;
  double s = 0.0, s2 = 0.0;
  const int E = B_ * N_ * KNB;
  for (int e0 = blockIdx.x * 2; e0 < E; e0 += gridDim.x * 2) {
    int e = e0 + which;
    int p = e / KNB;
    int nb = nbr[e] & (N_ - 1);
    int base = (p >> 12) << 12;
    float y = __bfloat162float(a[(base + nb) * 128 + o]) + __bfloat162float(ac[p * 128 + o]);
    s += (double)y; s2 += (double)y * (double)y;
  }
  atomicAdd(&st[o], s);
  atomicAdd(&st[128 + o], s2);
}

// ---------------- BN finalize ----------------
__global__ void bnfin_kernel(const double* __restrict__ st, const float* __restrict__ g,
                             const float* __restrict__ bi, float* __restrict__ so,
                             int nch, double cnt)
{
  int o = threadIdx.x;
  if (o >= nch) return;
  double mu = st[o] / cnt;
  double var = st[nch + o] / cnt - mu * mu;
  double sc = (double)g[o] / sqrt(var + 1e-5);
  so[o] = (float)sc;
  so[nch + o] = (float)((double)bi[o] - mu * sc);
}

// ---------------- h1 = max_k lrelu(bn(u[nbr]+uc[ctr])) ----------------
__global__ __launch_bounds__(256)
void h1_kernel(const bf16* __restrict__ u, const bf16* __restrict__ uc,
               const int* __restrict__ idx1, const float* __restrict__ so,
               bf16* __restrict__ h1)
{
  const int o = threadIdx.x & 127, which = threadIdx.x >> 7;
  float sc = so[o], off = so[128 + o];
  for (int p0 = blockIdx.x * 2; p0 < B_ * N_; p0 += gridDim.x * 2) {
    int p = p0 + which;
    int base = (p >> 12) << 12;
    float ucv = __bfloat162float(uc[p * 128 + o]);
    float m = -3.0e38f;
#pragma unroll
    for (int kk = 0; kk < K14_; ++kk) {
      int nb = idx1[p * K14_ + kk] & (N_ - 1);
      float y = __bfloat162float(u[(base + nb) * 128 + o]) + ucv;
      float v = fmaf(y, sc, off);
      v = v > 0.f ? v : 0.2f * v;
      m = fmaxf(m, v);
    }
    h1[p * 128 + o] = __float2bfloat16(m);
  }
}

// ---------------- conv3: point-major, wave-autonomous, no block barriers -------
// PASS 0: accumulate BN3 stats over y3.  PASS 1: bn3 + lrelu + max_k -> out.
template<int PASS>
__global__ __launch_bounds__(256)
void conv3_kernel(const bf16* __restrict__ z, const bf16* __restrict__ zc,
                  const int* __restrict__ idx2, const float* __restrict__ so2,
                  const float* __restrict__ so3, const float* __restrict__ W3T,
                  double* __restrict__ st3, float* __restrict__ outp)
{
  __shared__ float w3[128 * 64];        // [c][oo], 32 KB, block-shared
  __shared__ float h2s[4][128 * 12];    // per-wave [c][12] (8 edges used), 24 KB
  for (int e = threadIdx.x; e < 128 * 64; e += 256) w3[e] = W3T[e];
  __syncthreads();
  const int wave = threadIdx.x >> 6, lane = threadIdx.x & 63;
  float* h2w = &h2s[wave][0];
  const float sc20 = so2[lane],      off20 = so2[128 + lane];
  const float sc21 = so2[64 + lane], off21 = so2[192 + lane];
  float sc3 = 0.f, off3 = 0.f;
  if constexpr (PASS == 1) { sc3 = so3[lane]; off3 = so3[64 + lane]; }
  double s = 0.0, s2 = 0.0;
  const int gw = blockIdx.x * 4 + wave;           // 2048 waves
  for (int p = gw; p < B_ * N_; p += 2048) {
    const int base = (p >> 12) << 12;
    const float zc0 = __bfloat162float(zc[p * 128 + lane]);
    const float zc1 = __bfloat162float(zc[p * 128 + 64 + lane]);
    float m = -3.0e38f;
#pragma unroll
    for (int kc = 0; kc < 4; ++kc) {
      asm volatile("s_waitcnt lgkmcnt(0)" ::: "memory");   // WAR vs prev chunk reads
#pragma unroll
      for (int i = 0; i < 8; ++i) {
        int nb = idx2[p * K2_ + kc * 8 + i] & (N_ - 1);
        float y0 = __bfloat162float(z[(base + nb) * 128 + lane]) + zc0;
        float y1 = __bfloat162float(z[(base + nb) * 128 + 64 + lane]) + zc1;
        float v0 = fmaf(y0, sc20, off20); v0 = v0 > 0.f ? v0 : 0.2f * v0;
        float v1 = fmaf(y1, sc21, off21); v1 = v1 > 0.f ? v1 : 0.2f * v1;
        h2w[lane * 12 + i] = v0;
        h2w[(lane + 64) * 12 + i] = v1;
      }
      asm volatile("s_waitcnt lgkmcnt(0)" ::: "memory");   // RAW: writes visible
      float a0 = 0.f, a1 = 0.f, a2 = 0.f, a3 = 0.f;
      float a4 = 0.f, a5 = 0.f, a6 = 0.f, a7 = 0.f;
#pragma unroll 4
      for (int c = 0; c < 128; ++c) {
        float wv = w3[(c << 6) | lane];
        float4 ha = *(const float4*)&h2w[c * 12];
        float4 hb = *(const float4*)&h2w[c * 12 + 4];
        a0 = fmaf(wv, ha.x, a0); a1 = fmaf(wv, ha.y, a1);
        a2 = fmaf(wv, ha.z, a2); a3 = fmaf(wv, ha.w, a3);
        a4 = fmaf(wv, hb.x, a4); a5 = fmaf(wv, hb.y, a5);
        a6 = fmaf(wv, hb.z, a6); a7 = fmaf(wv, hb.w, a7);
      }
      if constexpr (PASS == 0) {
        s += (double)a0 + (double)a1 + (double)a2 + (double)a3
           + (double)a4 + (double)a5 + (double)a6 + (double)a7;
        s2 += (double)a0 * a0 + (double)a1 * a1 + (double)a2 * a2 + (double)a3 * a3
            + (double)a4 * a4 + (double)a5 * a5 + (double)a6 * a6 + (double)a7 * a7;
      } else {
        float v;
        v = fmaf(a0, sc3, off3); v = v > 0.f ? v : 0.2f * v; m = fmaxf(m, v);
        v = fmaf(a1, sc3, off3); v = v > 0.f ? v : 0.2f * v; m = fmaxf(m, v);
        v = fmaf(a2, sc3, off3); v = v > 0.f ? v : 0.2f * v; m = fmaxf(m, v);
        v = fmaf(a3, sc3, off3); v = v > 0.f ? v : 0.2f * v; m = fmaxf(m, v);
        v = fmaf(a4, sc3, off3); v = v > 0.f ? v : 0.2f * v; m = fmaxf(m, v);
        v = fmaf(a5, sc3, off3); v = v > 0.f ? v : 0.2f * v; m = fmaxf(m, v);
        v = fmaf(a6, sc3, off3); v = v > 0.f ? v : 0.2f * v; m = fmaxf(m, v);
        v = fmaf(a7, sc3, off3); v = v > 0.f ? v : 0.2f * v; m = fmaxf(m, v);
      }
    }
    if constexpr (PASS == 1) outp[p * OC_ + lane] = m;
  }
  if constexpr (PASS == 0) {
    atomicAdd(&st3[lane], s);
    atomicAdd(&st3[64 + lane], s2);
  }
}

} // namespace

extern "C" void kernel_launch(void* const* d_in, const int* in_sizes, int n_in,
                              void* d_out, int out_size, void* d_ws, size_t ws_size,
                              hipStream_t stream) {
  const float* x   = (const float*)d_in[0];
  const float* pos = (const float*)d_in[1];
  const float* W1  = (const float*)d_in[2];
  const float* g1  = (const float*)d_in[3];
  const float* b1  = (const float*)d_in[4];
  const float* W2  = (const float*)d_in[5];
  const float* g2  = (const float*)d_in[6];
  const float* b2  = (const float*)d_in[7];
  const float* W3  = (const float*)d_in[8];
  const float* g3  = (const float*)d_in[9];
  const float* b3  = (const float*)d_in[10];

  float* outp = (float*)d_out;                 // [B*N*64] float
  float* oidx = outp + B_ * N_ * OC_;          // [B*N*32] idx2 as float values

  char* w = (char*)d_ws;
  double* stats = (double*)w;            w += 640 * sizeof(double);
  float* nxf    = (float*)w;             w += B_ * N_ * 4;
  float* WT1a   = (float*)w;             w += 64 * 128 * 4;
  float* WT1bm  = (float*)w;             w += 64 * 128 * 4;
  float* WT2a   = (float*)w;             w += 128 * 128 * 4;
  float* WT2bm  = (float*)w;             w += 128 * 128 * 4;
  float* W3T    = (float*)w;             w += 128 * 64 * 4;
  float* so1    = (float*)w;             w += 256 * 4;
  float* so2    = (float*)w;             w += 256 * 4;
  float* so3    = (float*)w;             w += 128 * 4;
  int* idx1     = (int*)w;               w += B_ * N_ * K14_ * 4;
  int* idx2i    = (int*)w;               w += B_ * N_ * K2_ * 4;
  bf16* u       = (bf16*)w;              w += B_ * N_ * 128 * 2;
  bf16* uc      = (bf16*)w;              w += B_ * N_ * 128 * 2;
  bf16* h1      = (bf16*)w;              w += B_ * N_ * 128 * 2;
  bf16* zz  = u;    // alias: u dead after h1_kernel
  bf16* zzc = uc;   // alias: uc dead after h1_kernel

  hipMemsetAsync(stats, 0, 640 * sizeof(double), stream);

  xnorm_kernel<<<(B_ * N_ + 255) / 256, 256, 0, stream>>>(x, nxf);
  wprep_kernel<<<64, 256, 0, stream>>>(W1, W2, W3, WT1a, WT1bm, WT2a, WT2bm, W3T);

  knn_x_kernel<<<1024, 512, 0, stream>>>(x, nxf, idx1);
  knn_pos_kernel<<<1024, 512, 0, stream>>>(pos, idx1, idx2i, oidx);

  lin_kernel<64, float><<<512, 256, 0, stream>>>(x, WT1a, u);
  lin_kernel<64, float><<<512, 256, 0, stream>>>(x, WT1bm, uc);

  stats_gather_kernel<K14_><<<512, 256, 0, stream>>>(u, uc, idx1, stats);
  bnfin_kernel<<<1, 128, 0, stream>>>(stats, g1, b1, so1, 128, (double)(B_ * N_ * K14_));
  h1_kernel<<<512, 256, 0, stream>>>(u, uc, idx1, so1, h1);

  lin_kernel<128, bf16><<<512, 256, 0, stream>>>(h1, WT2a, zz);
  lin_kernel<128, bf16><<<512, 256, 0, stream>>>(h1, WT2bm, zzc);

  stats_gather_kernel<K2_><<<512, 256, 0, stream>>>(zz, zzc, idx2i, stats + 256);
  bnfin_kernel<<<1, 128, 0, stream>>>(stats + 256, g2, b2, so2, 128, (double)(B_ * N_ * K2_));

  conv3_kernel<0><<<512, 256, 0, stream>>>(zz, zzc, idx2i, so2, nullptr, W3T, stats + 512, nullptr);
  bnfin_kernel<<<1, 128, 0, stream>>>(stats + 512, g3, b3, so3, 64, (double)(B_ * N_ * K2_));
  conv3_kernel<1><<<512, 256, 0, stream>>>(zz, zzc, idx2i, so2, so3, W3T, nullptr, outp);
}

// Round 7
// 898.775 us; speedup vs baseline: 2.4677x; 1.1293x over previous
//
#include <hip/hip_runtime.h>
#include <hip/hip_bf16.h>
#include <type_traits>

using bf16 = __hip_bfloat16;

namespace {

constexpr int B_ = 2;
constexpr int N_ = 4096;
constexpr int C_ = 64;
constexpr int K14_ = 14;
constexpr int KX_ = 8;
constexpr int KP_ = 6;
constexpr int K2_ = 32;
constexpr int OC_ = 64;

__device__ __forceinline__ float bflo(unsigned u) { return __uint_as_float(u << 16); }
__device__ __forceinline__ float bfhi(unsigned u) { return __uint_as_float(u & 0xffff0000u); }

// Hierarchical per-lane selection state: 8 named groups over dst[64] + taken mask.
// Strict-less + ascending order == lowest-slot tie-break (matches stable top_k since
// slot->j is monotonic per lane in both knn kernels).
#define GRP8_ONE(GV, GS, T) \
  { bool av = !((taken >> (T)) & 1ull); bool bb = av && dst[T] < GV; \
    GV = bb ? dst[T] : GV; GS = bb ? (T) : GS; }
#define GRP8(GV, GS, B) do { GV = 3.0e38f; GS = B; \
  GRP8_ONE(GV, GS, (B)+0) GRP8_ONE(GV, GS, (B)+1) GRP8_ONE(GV, GS, (B)+2) \
  GRP8_ONE(GV, GS, (B)+3) GRP8_ONE(GV, GS, (B)+4) GRP8_ONE(GV, GS, (B)+5) \
  GRP8_ONE(GV, GS, (B)+6) GRP8_ONE(GV, GS, (B)+7) } while (0)
#define GTREE_ONE(GV, GS) { bool bb = GV < pv; pv = bb ? GV : pv; ptt = bb ? GS : ptt; }
#define GTREE() do { pv = gv0; ptt = gs0; \
  GTREE_ONE(gv1, gs1) GTREE_ONE(gv2, gs2) GTREE_ONE(gv3, gs3) GTREE_ONE(gv4, gs4) \
  GTREE_ONE(gv5, gs5) GTREE_ONE(gv6, gs6) GTREE_ONE(gv7, gs7) } while (0)
#define GRP_SWITCH(TT) do { switch ((TT) >> 3) { \
  case 0: GRP8(gv0, gs0, 0);  break; case 1: GRP8(gv1, gs1, 8);  break; \
  case 2: GRP8(gv2, gs2, 16); break; case 3: GRP8(gv3, gs3, 24); break; \
  case 4: GRP8(gv4, gs4, 32); break; case 5: GRP8(gv5, gs5, 40); break; \
  case 6: GRP8(gv6, gs6, 48); break; case 7: GRP8(gv7, gs7, 56); break; } \
  GTREE(); } while (0)
#define SEL_DECL float gv0, gv1, gv2, gv3, gv4, gv5, gv6, gv7; \
  int gs0, gs1, gs2, gs3, gs4, gs5, gs6, gs7; float pv; int ptt; \
  unsigned long long taken = 0ull;
#define SEL_INIT do { \
  GRP8(gv0, gs0, 0);  GRP8(gv1, gs1, 8);  GRP8(gv2, gs2, 16); GRP8(gv3, gs3, 24); \
  GRP8(gv4, gs4, 32); GRP8(gv5, gs5, 40); GRP8(gv6, gs6, 48); GRP8(gv7, gs7, 56); \
  GTREE(); } while (0)

// ---------------- x squared norms (f32) ----------------
__global__ __launch_bounds__(256)
void xnorm_kernel(const float* __restrict__ x, float* __restrict__ nx)
{
  int p = blockIdx.x * 256 + threadIdx.x;
  if (p >= B_ * N_) return;
  float s = 0.f;
#pragma unroll 8
  for (int c = 0; c < C_; ++c) { float v = x[p * C_ + c]; s = fmaf(v, v, s); }
  nx[p] = s;
}

// ---------------- weight prep: split + transpose ----------------
__global__ __launch_bounds__(256)
void wprep_kernel(const float* __restrict__ W1, const float* __restrict__ W2,
                  const float* __restrict__ W3,
                  float* __restrict__ WT1a, float* __restrict__ WT1bm,
                  float* __restrict__ WT2a, float* __restrict__ WT2bm,
                  float* __restrict__ W3T)
{
  int idx = blockIdx.x * 256 + threadIdx.x;
  if (idx < 128 * 128) {
    int o = idx & 127, c = idx >> 7;
    float a = W2[o * 256 + c];
    WT2a[c * 128 + o] = a;
    WT2bm[c * 128 + o] = W2[o * 256 + 128 + c] - a;
    if (c < 64) {
      float a1 = W1[o * 128 + c];
      WT1a[c * 128 + o] = a1;
      WT1bm[c * 128 + o] = W1[o * 128 + 64 + c] - a1;
    }
  }
  if (idx < 64 * 128) {
    int oo = idx & 63, c = idx >> 6;
    W3T[c * 64 + oo] = W3[oo * 128 + c];
  }
}

// ---------------- knn over x v3: conflict-free LDS, hierarchical selection ------
// tile_u32[c][j2]: packed bf16 pair (neighbors 2*j2, 2*j2+1); row stride 131 (odd).
// Lane owns neighbors {2L,2L+1,128+2L,128+2L+1} per 256-tile.
// slot tt: j = (tt>>2)*256 + ((tt>>1)&1)*128 + 2*lane + (tt&1)   (monotonic in tt)
__global__ __launch_bounds__(512, 2)
void knn_x_kernel(const float* __restrict__ x, const float* __restrict__ nx,
                  int* __restrict__ idx1)
{
  __shared__ float qs[8][C_];
  __shared__ unsigned tileu[C_ * 131];
  const int wave = threadIdx.x >> 6, lane = threadIdx.x & 63;
  const int qg = blockIdx.x * 8 + wave;       // 1024 blocks * 8 waves
  const int bb = qg >> 12;
  const float* xb = x + bb * N_ * C_;
  qs[wave][lane] = x[qg * C_ + lane];
  const float nq = nx[qg];
  const float* nb_ = nx + bb * N_;
  float dst[64];
#pragma unroll
  for (int ti = 0; ti < 16; ++ti) {
    __syncthreads();
    for (int e = threadIdx.x; e < C_ * 128; e += 512) {
      int c = e & 63, j2 = e >> 6;
      float x0 = xb[(ti * 256 + 2 * j2) * 64 + c];
      float x1 = xb[(ti * 256 + 2 * j2 + 1) * 64 + c];
      tileu[c * 131 + j2] = (__float_as_uint(x0) >> 16) | (__float_as_uint(x1) & 0xffff0000u);
    }
    __syncthreads();
    float a0 = 0.f, a1 = 0.f, a2 = 0.f, a3 = 0.f;
#pragma unroll 8
    for (int c = 0; c < C_; ++c) {
      unsigned u0 = tileu[c * 131 + lane];
      unsigned u1 = tileu[c * 131 + 64 + lane];
      float q = qs[wave][c];
      a0 = fmaf(q, bflo(u0), a0);
      a1 = fmaf(q, bfhi(u0), a1);
      a2 = fmaf(q, bflo(u1), a2);
      a3 = fmaf(q, bfhi(u1), a3);
    }
    float2 n01 = *(const float2*)&nb_[ti * 256 + 2 * lane];
    float2 n23 = *(const float2*)&nb_[ti * 256 + 128 + 2 * lane];
    dst[ti * 4 + 0] = nq + n01.x - 2.f * a0;
    dst[ti * 4 + 1] = nq + n01.y - 2.f * a1;
    dst[ti * 4 + 2] = nq + n23.x - 2.f * a2;
    dst[ti * 4 + 3] = nq + n23.y - 2.f * a3;
  }
  SEL_DECL;
  SEL_INIT;
  for (int r = 0; r < KX_ + 1; ++r) {
    float d = pv;
    int j = ((ptt >> 2) << 8) + (((ptt >> 1) & 1) << 7) + 2 * lane + (ptt & 1);
#pragma unroll
    for (int m = 1; m < 64; m <<= 1) {
      float od = __shfl_xor(d, m, 64);
      int oj = __shfl_xor(j, m, 64);
      if (od < d || (od == d && oj < j)) { d = od; j = oj; }
    }
    if (r > 0 && lane == 0) idx1[qg * K14_ + (r - 1)] = j;
    if (((j >> 1) & 63) == lane) {
      int tt = ((j >> 8) << 2) | (((j >> 7) & 1) << 1) | (j & 1);
      taken |= 1ull << tt;
      GRP_SWITCH(tt);
    }
  }
}

// ---------------- knn over pos: bit-exact numpy-f32 distances (graded idx2) -----
// Distance arithmetic UNCHANGED from the passing R5 version. Selection upgraded to
// hierarchical exact (d, j) extraction — identical ordering semantics.
__global__ __launch_bounds__(512, 2)
void knn_pos_kernel(const float* __restrict__ pos,
                    int* __restrict__ idx1, int* __restrict__ idx2,
                    float* __restrict__ oidx)
{
#pragma clang fp contract(off)
  __shared__ float pL[3][N_];
  __shared__ float nL[N_];
  const int wave = threadIdx.x >> 6, lane = threadIdx.x & 63;
  const int qg = blockIdx.x * 8 + wave;
  const int bb = qg >> 12;
  const float* pb = pos + bb * N_ * 3;
  for (int j = threadIdx.x; j < N_; j += 512) {
    float a = pb[j * 3], b = pb[j * 3 + 1], c = pb[j * 3 + 2];
    pL[0][j] = a; pL[1][j] = b; pL[2][j] = c;
    float aa = a * a;
    float bb2 = b * b;
    float cc = c * c;
    float s1 = aa + bb2;
    nL[j] = s1 + cc;
  }
  __syncthreads();
  const int q = qg & (N_ - 1);
  const float qx = pL[0][q], qy = pL[1][q], qz = pL[2][q];
  const float nq = nL[q];
  float dst[64];
#pragma unroll
  for (int t = 0; t < 64; ++t) {
    int j = t * 64 + lane;
    float dot = qx * pL[0][j];
    dot = fmaf(qy, pL[1][j], dot);
    dot = fmaf(qz, pL[2][j], dot);
    float t1 = nq + nL[j];
    float t2 = 2.0f * dot;
    dst[t] = t1 - t2;
  }
  SEL_DECL;
  SEL_INIT;
  for (int r = 0; r < K2_ + 1; ++r) {
    float d = pv;
    int j = ptt * 64 + lane;
#pragma unroll
    for (int m = 1; m < 64; m <<= 1) {
      float od = __shfl_xor(d, m, 64);
      int oj = __shfl_xor(j, m, 64);
      if (od < d || (od == d && oj < j)) { d = od; j = oj; }
    }
    if (r > 0 && lane == 0) {
      int rr = r - 1;
      if (rr < KP_) idx1[qg * K14_ + KX_ + rr] = j;
      idx2[qg * K2_ + rr] = j;
      oidx[qg * K2_ + rr] = (float)j;
    }
    if ((j & 63) == lane) {
      int tt = j >> 6;
      taken |= 1ull << tt;
      GRP_SWITCH(tt);
    }
  }
}

// ---------------- per-point projection ----------------
template<int CIN, typename TIN>
__global__ __launch_bounds__(256)
void lin_kernel(const TIN* __restrict__ in, const float* __restrict__ WT,
                bf16* __restrict__ out)
{
  __shared__ float wt[CIN * 128];
  for (int e = threadIdx.x; e < CIN * 128; e += 256) wt[e] = WT[e];
  __syncthreads();
  const int which = threadIdx.x >> 7, o = threadIdx.x & 127;
  for (int p0 = blockIdx.x * 2; p0 < B_ * N_; p0 += gridDim.x * 2) {
    int p = p0 + which;
    float acc = 0.f;
#pragma unroll 8
    for (int c = 0; c < CIN; ++c) {
      float v;
      if constexpr (std::is_same_v<TIN, float>) v = in[p * CIN + c];
      else v = __bfloat162float(in[p * CIN + c]);
      acc = fmaf(wt[c * 128 + o], v, acc);
    }
    out[p * 128 + o] = __float2bfloat16(acc);
  }
}

// ---------------- BN stats over gathered y = a[nbr] + ac[ctr] ----------------
template<int KNB>
__global__ __launch_bounds__(256)
void stats_gather_kernel(const bf16* __restrict__ a, const bf16* __restrict__ ac,
                         const int* __restrict__ nbr, double* __restrict__ st)
{
  const int o = threadIdx.x & 127;
  const int which = threadIdx.x >> 7;
  double s = 0.0, s2 = 0.0;
  const int E = B_ * N_ * KNB;
  for (int e0 = blockIdx.x * 2; e0 < E; e0 += gridDim.x * 2) {
    int e = e0 + which;
    int p = e / KNB;
    int nb = nbr[e] & (N_ - 1);
    int base = (p >> 12) << 12;
    float y = __bfloat162float(a[(base + nb) * 128 + o]) + __bfloat162float(ac[p * 128 + o]);
    s += (double)y; s2 += (double)y * (double)y;
  }
  atomicAdd(&st[o], s);
  atomicAdd(&st[128 + o], s2);
}

// ---------------- BN finalize ----------------
__global__ void bnfin_kernel(const double* __restrict__ st, const float* __restrict__ g,
                             const float* __restrict__ bi, float* __restrict__ so,
                             int nch, double cnt)
{
  int o = threadIdx.x;
  if (o >= nch) return;
  double mu = st[o] / cnt;
  double var = st[nch + o] / cnt - mu * mu;
  double sc = (double)g[o] / sqrt(var + 1e-5);
  so[o] = (float)sc;
  so[nch + o] = (float)((double)bi[o] - mu * sc);
}

// ---------------- h1 = max_k lrelu(bn(u[nbr]+uc[ctr])) ----------------
__global__ __launch_bounds__(256)
void h1_kernel(const bf16* __restrict__ u, const bf16* __restrict__ uc,
               const int* __restrict__ idx1, const float* __restrict__ so,
               bf16* __restrict__ h1)
{
  const int o = threadIdx.x & 127, which = threadIdx.x >> 7;
  float sc = so[o], off = so[128 + o];
  for (int p0 = blockIdx.x * 2; p0 < B_ * N_; p0 += gridDim.x * 2) {
    int p = p0 + which;
    int base = (p >> 12) << 12;
    float ucv = __bfloat162float(uc[p * 128 + o]);
    float m = -3.0e38f;
#pragma unroll
    for (int kk = 0; kk < K14_; ++kk) {
      int nb = idx1[p * K14_ + kk] & (N_ - 1);
      float y = __bfloat162float(u[(base + nb) * 128 + o]) + ucv;
      float v = fmaf(y, sc, off);
      v = v > 0.f ? v : 0.2f * v;
      m = fmaxf(m, v);
    }
    h1[p * 128 + o] = __float2bfloat16(m);
  }
}

// ---------------- conv3: point-major, wave-autonomous, no block barriers -------
template<int PASS>
__global__ __launch_bounds__(256)
void conv3_kernel(const bf16* __restrict__ z, const bf16* __restrict__ zc,
                  const int* __restrict__ idx2, const float* __restrict__ so2,
                  const float* __restrict__ so3, const float* __restrict__ W3T,
                  double* __restrict__ st3, float* __restrict__ outp)
{
  __shared__ float w3[128 * 64];
  __shared__ float h2s[4][128 * 12];
  for (int e = threadIdx.x; e < 128 * 64; e += 256) w3[e] = W3T[e];
  __syncthreads();
  const int wave = threadIdx.x >> 6, lane = threadIdx.x & 63;
  float* h2w = &h2s[wave][0];
  const float sc20 = so2[lane],      off20 = so2[128 + lane];
  const float sc21 = so2[64 + lane], off21 = so2[192 + lane];
  float sc3 = 0.f, off3 = 0.f;
  if constexpr (PASS == 1) { sc3 = so3[lane]; off3 = so3[64 + lane]; }
  double s = 0.0, s2 = 0.0;
  const int gw = blockIdx.x * 4 + wave;
  for (int p = gw; p < B_ * N_; p += 2048) {
    const int base = (p >> 12) << 12;
    const float zc0 = __bfloat162float(zc[p * 128 + lane]);
    const float zc1 = __bfloat162float(zc[p * 128 + 64 + lane]);
    float m = -3.0e38f;
#pragma unroll
    for (int kc = 0; kc < 4; ++kc) {
      asm volatile("s_waitcnt lgkmcnt(0)" ::: "memory");
#pragma unroll
      for (int i = 0; i < 8; ++i) {
        int nb = idx2[p * K2_ + kc * 8 + i] & (N_ - 1);
        float y0 = __bfloat162float(z[(base + nb) * 128 + lane]) + zc0;
        float y1 = __bfloat162float(z[(base + nb) * 128 + 64 + lane]) + zc1;
        float v0 = fmaf(y0, sc20, off20); v0 = v0 > 0.f ? v0 : 0.2f * v0;
        float v1 = fmaf(y1, sc21, off21); v1 = v1 > 0.f ? v1 : 0.2f * v1;
        h2w[lane * 12 + i] = v0;
        h2w[(lane + 64) * 12 + i] = v1;
      }
      asm volatile("s_waitcnt lgkmcnt(0)" ::: "memory");
      float a0 = 0.f, a1 = 0.f, a2 = 0.f, a3 = 0.f;
      float a4 = 0.f, a5 = 0.f, a6 = 0.f, a7 = 0.f;
#pragma unroll 4
      for (int c = 0; c < 128; ++c) {
        float wv = w3[(c << 6) | lane];
        float4 ha = *(const float4*)&h2w[c * 12];
        float4 hb = *(const float4*)&h2w[c * 12 + 4];
        a0 = fmaf(wv, ha.x, a0); a1 = fmaf(wv, ha.y, a1);
        a2 = fmaf(wv, ha.z, a2); a3 = fmaf(wv, ha.w, a3);
        a4 = fmaf(wv, hb.x, a4); a5 = fmaf(wv, hb.y, a5);
        a6 = fmaf(wv, hb.z, a6); a7 = fmaf(wv, hb.w, a7);
      }
      if constexpr (PASS == 0) {
        s += (double)a0 + (double)a1 + (double)a2 + (double)a3
           + (double)a4 + (double)a5 + (double)a6 + (double)a7;
        s2 += (double)a0 * a0 + (double)a1 * a1 + (double)a2 * a2 + (double)a3 * a3
            + (double)a4 * a4 + (double)a5 * a5 + (double)a6 * a6 + (double)a7 * a7;
      } else {
        float v;
        v = fmaf(a0, sc3, off3); v = v > 0.f ? v : 0.2f * v; m = fmaxf(m, v);
        v = fmaf(a1, sc3, off3); v = v > 0.f ? v : 0.2f * v; m = fmaxf(m, v);
        v = fmaf(a2, sc3, off3); v = v > 0.f ? v : 0.2f * v; m = fmaxf(m, v);
        v = fmaf(a3, sc3, off3); v = v > 0.f ? v : 0.2f * v; m = fmaxf(m, v);
        v = fmaf(a4, sc3, off3); v = v > 0.f ? v : 0.2f * v; m = fmaxf(m, v);
        v = fmaf(a5, sc3, off3); v = v > 0.f ? v : 0.2f * v; m = fmaxf(m, v);
        v = fmaf(a6, sc3, off3); v = v > 0.f ? v : 0.2f * v; m = fmaxf(m, v);
        v = fmaf(a7, sc3, off3); v = v > 0.f ? v : 0.2f * v; m = fmaxf(m, v);
      }
    }
    if constexpr (PASS == 1) outp[p * OC_ + lane] = m;
  }
  if constexpr (PASS == 0) {
    atomicAdd(&st3[lane], s);
    atomicAdd(&st3[64 + lane], s2);
  }
}

} // namespace

extern "C" void kernel_launch(void* const* d_in, const int* in_sizes, int n_in,
                              void* d_out, int out_size, void* d_ws, size_t ws_size,
                              hipStream_t stream) {
  const float* x   = (const float*)d_in[0];
  const float* pos = (const float*)d_in[1];
  const float* W1  = (const float*)d_in[2];
  const float* g1  = (const float*)d_in[3];
  const float* b1  = (const float*)d_in[4];
  const float* W2  = (const float*)d_in[5];
  const float* g2  = (const float*)d_in[6];
  const float* b2  = (const float*)d_in[7];
  const float* W3  = (const float*)d_in[8];
  const float* g3  = (const float*)d_in[9];
  const float* b3  = (const float*)d_in[10];

  float* outp = (float*)d_out;                 // [B*N*64] float
  float* oidx = outp + B_ * N_ * OC_;          // [B*N*32] idx2 as float values

  char* w = (char*)d_ws;
  double* stats = (double*)w;            w += 640 * sizeof(double);
  float* nxf    = (float*)w;             w += B_ * N_ * 4;
  float* WT1a   = (float*)w;             w += 64 * 128 * 4;
  float* WT1bm  = (float*)w;             w += 64 * 128 * 4;
  float* WT2a   = (float*)w;             w += 128 * 128 * 4;
  float* WT2bm  = (float*)w;             w += 128 * 128 * 4;
  float* W3T    = (float*)w;             w += 128 * 64 * 4;
  float* so1    = (float*)w;             w += 256 * 4;
  float* so2    = (float*)w;             w += 256 * 4;
  float* so3    = (float*)w;             w += 128 * 4;
  int* idx1     = (int*)w;               w += B_ * N_ * K14_ * 4;
  int* idx2i    = (int*)w;               w += B_ * N_ * K2_ * 4;
  bf16* u       = (bf16*)w;              w += B_ * N_ * 128 * 2;
  bf16* uc      = (bf16*)w;              w += B_ * N_ * 128 * 2;
  bf16* h1      = (bf16*)w;              w += B_ * N_ * 128 * 2;
  bf16* zz  = u;    // alias: u dead after h1_kernel
  bf16* zzc = uc;   // alias: uc dead after h1_kernel

  hipMemsetAsync(stats, 0, 640 * sizeof(double), stream);

  xnorm_kernel<<<(B_ * N_ + 255) / 256, 256, 0, stream>>>(x, nxf);
  wprep_kernel<<<64, 256, 0, stream>>>(W1, W2, W3, WT1a, WT1bm, WT2a, WT2bm, W3T);

  knn_x_kernel<<<1024, 512, 0, stream>>>(x, nxf, idx1);
  knn_pos_kernel<<<1024, 512, 0, stream>>>(pos, idx1, idx2i, oidx);

  lin_kernel<64, float><<<512, 256, 0, stream>>>(x, WT1a, u);
  lin_kernel<64, float><<<512, 256, 0, stream>>>(x, WT1bm, uc);

  stats_gather_kernel<K14_><<<512, 256, 0, stream>>>(u, uc, idx1, stats);
  bnfin_kernel<<<1, 128, 0, stream>>>(stats, g1, b1, so1, 128, (double)(B_ * N_ * K14_));
  h1_kernel<<<512, 256, 0, stream>>>(u, uc, idx1, so1, h1);

  lin_kernel<128, bf16><<<512, 256, 0, stream>>>(h1, WT2a, zz);
  lin_kernel<128, bf16><<<512, 256, 0, stream>>>(h1, WT2bm, zzc);

  stats_gather_kernel<K2_><<<512, 256, 0, stream>>>(zz, zzc, idx2i, stats + 256);
  bnfin_kernel<<<1, 128, 0, stream>>>(stats + 256, g2, b2, so2, 128, (double)(B_ * N_ * K2_));

  conv3_kernel<0><<<512, 256, 0, stream>>>(zz, zzc, idx2i, so2, nullptr, W3T, stats + 512, nullptr);
  bnfin_kernel<<<1, 128, 0, stream>>>(stats + 512, g3, b3, so3, 64, (double)(B_ * N_ * K2_));
  conv3_kernel<1><<<512, 256, 0, stream>>>(zz, zzc, idx2i, so2, so3, W3T, nullptr, outp);
}